// Round 1
// baseline (162.346 us; speedup 1.0000x reference)
//
#include <hip/hip_runtime.h>
#include <cstdint>

#define L_SEQ 2048
#define NH 16
#define EDIM 64
#define WINDOW 1024
#define QT 64      // queries per block (4 waves x 16)
#define KT 64      // keys per LDS tile
#define LOG2E 1.4426950408889634f

typedef short bf16x8 __attribute__((ext_vector_type(8)));
typedef float f32x4 __attribute__((ext_vector_type(4)));

__device__ __forceinline__ short f2bf(float x) {
    uint32_t u = __builtin_bit_cast(uint32_t, x);
    uint32_t r = (u + 0x7fffu + ((u >> 16) & 1u)) >> 16;
    return (short)(r & 0xffffu);
}

// Block: 256 threads = 4 waves; wave w owns queries [qb + 16w, qb + 16w + 16).
// LDS: K tile [64 keys][72] bf16 (stride 72 -> 16B-aligned ds_read_b128, r/r+8 2-way banks = free)
//      V tile pre-swizzled into MFMA B-fragment order: frag (js,et) at vB[(js*4+et)*64*8], lane-major
//      P per-wave [16 q][72] bf16 for the C-layout -> A-layout round trip (m120 pattern)
__global__ __launch_bounds__(256, 2) void flexattn_fwd(
        const float* __restrict__ qkv, float* __restrict__ out) {
    __shared__ __align__(16) short kT[KT * 72];
    __shared__ __align__(16) short vB[8 * 64 * 8];
    __shared__ __align__(16) short pT[4][16 * 72];

    const int qtile = blockIdx.x;
    const int h     = blockIdx.y;
    const int b     = blockIdx.z;
    const int tid   = threadIdx.x;
    const int w     = tid >> 6;
    const int lane  = tid & 63;
    const int quad  = lane >> 4;
    const int r16   = lane & 15;

    const int qb = qtile * QT;
    const int rowstride = 3 * NH * EDIM;  // 3072 floats between consecutive l

    const float* qbase = qkv + ((size_t)b * L_SEQ * 3 + 0) * (NH * EDIM) + h * EDIM;
    const float* kbase = qkv + ((size_t)b * L_SEQ * 3 + 1) * (NH * EDIM) + h * EDIM;
    const float* vbase = qkv + ((size_t)b * L_SEQ * 3 + 2) * (NH * EDIM) + h * EDIM;

    // Q fragment (A-operand layout: Q[q=lane&15][e=quad*8+j]), pre-scaled by scale*log2(e)
    const float qscale = 0.125f * LOG2E;
    bf16x8 qfrag[2];
    {
        const int qg = qb + w * 16 + r16;
        const float* qrow = qbase + (size_t)qg * rowstride;
        #pragma unroll
        for (int es = 0; es < 2; ++es) {
            const float* p = qrow + es * 32 + quad * 8;
            float4 a = *(const float4*)p;
            float4 c = *(const float4*)(p + 4);
            bf16x8 f;
            f[0] = f2bf(a.x * qscale); f[1] = f2bf(a.y * qscale);
            f[2] = f2bf(a.z * qscale); f[3] = f2bf(a.w * qscale);
            f[4] = f2bf(c.x * qscale); f[5] = f2bf(c.y * qscale);
            f[6] = f2bf(c.z * qscale); f[7] = f2bf(c.w * qscale);
            qfrag[es] = f;
        }
    }

    const float slope2 = __builtin_amdgcn_exp2f(-8.0f * (float)(h + 1) / (float)NH) * LOG2E;

    f32x4 O[4] = {{0,0,0,0},{0,0,0,0},{0,0,0,0},{0,0,0,0}};
    float m_run[4] = {-1e30f, -1e30f, -1e30f, -1e30f};
    float l_run[4] = {0.f, 0.f, 0.f, 0.f};

    const int kmin = (qb >= WINDOW - 1) ? (qb - (WINDOW - 1)) : 0;
    const int t0 = kmin >> 6;
    const int t1 = qtile;   // last tile contains q = qb+63

    for (int kt = t0; kt <= t1; ++kt) {
        __syncthreads();    // previous tile's LDS reads done before overwrite
        {
            // stage 64 keys: thread t -> row j = t>>2, 16-float chunk (t&3)
            const int j = tid >> 2;
            const int ebase = (tid & 3) * 16;
            const float* krow = kbase + (size_t)(kt * KT + j) * rowstride + ebase;
            const float* vrow = vbase + (size_t)(kt * KT + j) * rowstride + ebase;
            const int js = j >> 5, qd = (j >> 3) & 3, ii = j & 7;
            #pragma unroll
            for (int ee = 0; ee < 4; ++ee) {
                const int e = ebase + ee * 4;
                float4 k4 = *(const float4*)(krow + ee * 4);
                short* kd = &kT[j * 72 + e];
                kd[0] = f2bf(k4.x); kd[1] = f2bf(k4.y);
                kd[2] = f2bf(k4.z); kd[3] = f2bf(k4.w);
                float4 v4 = *(const float4*)(vrow + ee * 4);
                const int et = e >> 4;
                const int ln = qd * 16 + (e & 15);
                short* vd = &vB[(((js * 4 + et) * 64) + ln) * 8 + ii];
                vd[0]  = f2bf(v4.x);
                vd[8]  = f2bf(v4.y);
                vd[16] = f2bf(v4.z);
                vd[24] = f2bf(v4.w);
            }
        }
        __syncthreads();

        // S = Q K^T, 16q x 64k per wave (scores already in log2 units)
        f32x4 S[4];
        #pragma unroll
        for (int ct = 0; ct < 4; ++ct) {
            const short* kr = &kT[(ct * 16 + r16) * 72 + quad * 8];
            bf16x8 b0 = *(const bf16x8*)kr;          // e in [quad*8, +8)
            bf16x8 b1 = *(const bf16x8*)(kr + 32);   // e in [32+quad*8, +8)
            f32x4 acc = {0.f, 0.f, 0.f, 0.f};
            acc = __builtin_amdgcn_mfma_f32_16x16x32_bf16(qfrag[0], b0, acc, 0, 0, 0);
            acc = __builtin_amdgcn_mfma_f32_16x16x32_bf16(qfrag[1], b1, acc, 0, 0, 0);
            S[ct] = acc;
        }

        // bias + mask; C-layout: q = quad*4 + r, k = ct*16 + r16
        const int q0 = qb + w * 16 + quad * 4;
        float p[4][4];
        float mt[4] = {-1e30f, -1e30f, -1e30f, -1e30f};
        #pragma unroll
        for (int ct = 0; ct < 4; ++ct) {
            const int kg = kt * KT + ct * 16 + r16;
            #pragma unroll
            for (int r = 0; r < 4; ++r) {
                const int dist = q0 + r - kg;
                float s2 = S[ct][r] - slope2 * (float)dist;
                if (dist < 0 || dist >= WINDOW) s2 = -1e30f;
                p[ct][r] = s2;
                mt[r] = fmaxf(mt[r], s2);
            }
        }
        // row max across the 16-lane group (butterfly, stays in-group for masks<16)
        #pragma unroll
        for (int d = 1; d < 16; d <<= 1) {
            #pragma unroll
            for (int r = 0; r < 4; ++r)
                mt[r] = fmaxf(mt[r], __shfl_xor(mt[r], d, 64));
        }

        float alpha[4], rs[4];
        #pragma unroll
        for (int r = 0; r < 4; ++r) {
            const float mn = fmaxf(m_run[r], mt[r]);
            alpha[r] = __builtin_amdgcn_exp2f(m_run[r] - mn);
            m_run[r] = mn;
            float s = 0.f;
            #pragma unroll
            for (int ct = 0; ct < 4; ++ct) {
                const float pe = __builtin_amdgcn_exp2f(p[ct][r] - mn);
                p[ct][r] = pe;
                s += pe;
            }
            rs[r] = s;
        }
        #pragma unroll
        for (int d = 1; d < 16; d <<= 1) {
            #pragma unroll
            for (int r = 0; r < 4; ++r)
                rs[r] += __shfl_xor(rs[r], d, 64);
        }
        #pragma unroll
        for (int r = 0; r < 4; ++r)
            l_run[r] = l_run[r] * alpha[r] + rs[r];
        #pragma unroll
        for (int et = 0; et < 4; ++et) {
            #pragma unroll
            for (int r = 0; r < 4; ++r)
                O[et][r] *= alpha[r];
        }

        // P: C-layout -> LDS -> A-layout (per-wave buffer; same-wave DS ops are in-order)
        short* pw = &pT[w][0];
        #pragma unroll
        for (int ct = 0; ct < 4; ++ct) {
            #pragma unroll
            for (int r = 0; r < 4; ++r)
                pw[(quad * 4 + r) * 72 + ct * 16 + r16] = f2bf(p[ct][r]);
        }
        bf16x8 aP0 = *(const bf16x8*)(pw + r16 * 72 + quad * 8);        // j in [quad*8,+8)
        bf16x8 aP1 = *(const bf16x8*)(pw + r16 * 72 + 32 + quad * 8);   // j in [32+quad*8,+8)

        // O += P V : B-frag (js,et) is one ds_read_b128 from the swizzled vB
        #pragma unroll
        for (int et = 0; et < 4; ++et) {
            bf16x8 v0 = *(const bf16x8*)(&vB[((0 * 4 + et) * 64 + lane) * 8]);
            O[et] = __builtin_amdgcn_mfma_f32_16x16x32_bf16(aP0, v0, O[et], 0, 0, 0);
            bf16x8 v1 = *(const bf16x8*)(&vB[((1 * 4 + et) * 64 + lane) * 8]);
            O[et] = __builtin_amdgcn_mfma_f32_16x16x32_bf16(aP1, v1, O[et], 0, 0, 0);
        }
    }

    // epilogue: out[b, q, h, e] = O / l
    float* obase = out + (((size_t)b * L_SEQ) * NH + (size_t)h) * EDIM;
    #pragma unroll
    for (int r = 0; r < 4; ++r) {
        const int qg = qb + w * 16 + quad * 4 + r;
        const float rl = 1.0f / l_run[r];
        float* orow = obase + (size_t)qg * (NH * EDIM);
        #pragma unroll
        for (int et = 0; et < 4; ++et)
            orow[et * 16 + r16] = O[et][r] * rl;
    }
}

extern "C" void kernel_launch(void* const* d_in, const int* in_sizes, int n_in,
                              void* d_out, int out_size, void* d_ws, size_t ws_size,
                              hipStream_t stream) {
    const float* qkv = (const float*)d_in[0];
    float* out = (float*)d_out;
    dim3 grid(L_SEQ / QT, NH, 2);
    flexattn_fwd<<<grid, 256, 0, stream>>>(qkv, out);
}

// Round 2
// 151.790 us; speedup vs baseline: 1.0695x; 1.0695x over previous
//
#include <hip/hip_runtime.h>
#include <cstdint>

#define L_SEQ 2048
#define NH 16
#define EDIM 64
#define WINDOW 1024
#define QT 64
#define KT 64
#define LOG2E 1.4426950408889634f

typedef short bf16x8 __attribute__((ext_vector_type(8)));
typedef float f32x4 __attribute__((ext_vector_type(4)));

__device__ __forceinline__ short f2bf(float x) {
    uint32_t u = __builtin_bit_cast(uint32_t, x);
    uint32_t r = (u + 0x7fffu + ((u >> 16) & 1u)) >> 16;
    return (short)(r & 0xffffu);
}

// async 16B/lane global->LDS: LDS dest = wave-uniform base + lane*16 (m104/m108)
__device__ __forceinline__ void async16(const short* g, const short* l) {
    __builtin_amdgcn_global_load_lds(
        (const __attribute__((address_space(1))) void*)(uintptr_t)(g),
        (__attribute__((address_space(3))) void*)(uintptr_t)(l),  // low 32 bits = LDS offset
        16, 0, 0);
}

// ---------------- pre-pass: fp32 qkv -> bf16 Q/K/V in MFMA-ready layouts ----------------
// tile t = (b<<9)|(h<<5)|tile ; each tensor stored as [t][512 chunks][8 bf16] (16B chunks)
// Q chunk  c = w*128 + es*64 + lane          : Q[qb+w*16+r16][es*32+quad*8+j] * qscale
// K chunk  c = row*8 + (cc ^ (row&7))        : K[row][cc*8+j]   (XOR swizzle -> conflict-free unpadded LDS)
// V chunk  c = (js*4+et)*64 + quad*16 + r16  : V[js*32+quad*8+j][et*16+r16]  (B-fragment order)
__global__ __launch_bounds__(256) void prepass(const float* __restrict__ qkv,
        short* __restrict__ qw, short* __restrict__ kw, short* __restrict__ vw) {
    const int t = blockIdx.x;
    const int b = t >> 9, h = (t >> 5) & 15, tile = t & 31;
    const int tid = threadIdx.x;
    const float* base = qkv + (size_t)b * (L_SEQ * 3072) + h * 64;
    const float qscale = 0.125f * LOG2E;
    short* qo = qw + (size_t)t * 4096;
    short* ko = kw + (size_t)t * 4096;
    short* vo = vw + (size_t)t * 4096;
    #pragma unroll
    for (int cc2 = 0; cc2 < 2; ++cc2) {
        const int c = tid + cc2 * 256;
        {   // Q
            const int w = c >> 7, es = (c >> 6) & 1, lane = c & 63;
            const int quad = lane >> 4, r16 = lane & 15;
            const int l = tile * 64 + w * 16 + r16;
            const float* src = base + (size_t)l * 3072 + es * 32 + quad * 8;
            float4 a = *(const float4*)src, d = *(const float4*)(src + 4);
            short* o = qo + (size_t)c * 8;
            o[0] = f2bf(a.x * qscale); o[1] = f2bf(a.y * qscale);
            o[2] = f2bf(a.z * qscale); o[3] = f2bf(a.w * qscale);
            o[4] = f2bf(d.x * qscale); o[5] = f2bf(d.y * qscale);
            o[6] = f2bf(d.z * qscale); o[7] = f2bf(d.w * qscale);
        }
        {   // K
            const int row = c >> 3, cc = (c & 7) ^ (row & 7);
            const int l = tile * 64 + row;
            const float* src = base + (size_t)l * 3072 + 1024 + cc * 8;
            float4 a = *(const float4*)src, d = *(const float4*)(src + 4);
            short* o = ko + (size_t)c * 8;
            o[0] = f2bf(a.x); o[1] = f2bf(a.y); o[2] = f2bf(a.z); o[3] = f2bf(a.w);
            o[4] = f2bf(d.x); o[5] = f2bf(d.y); o[6] = f2bf(d.z); o[7] = f2bf(d.w);
        }
        {   // V
            const int frag = c >> 6, l6 = c & 63;
            const int js = frag >> 2, et = frag & 3, quad = l6 >> 4, r16 = l6 & 15;
            const float* src = base + 2048 + (size_t)(tile * 64 + js * 32 + quad * 8) * 3072 + et * 16 + r16;
            short* o = vo + (size_t)c * 8;
            #pragma unroll
            for (int j = 0; j < 8; ++j) o[j] = f2bf(src[(size_t)j * 3072]);
        }
    }
}

// ---------------- attention (fast path): bf16 inputs, global_load_lds staging ----------------
__global__ __launch_bounds__(256, 2) void flexattn_fwd2(
        const short* __restrict__ qw, const short* __restrict__ kw,
        const short* __restrict__ vw, float* __restrict__ out) {
    __shared__ __align__(16) short kS[64 * 64];     // swizzled K tile image
    __shared__ __align__(16) short vS[512 * 8];     // B-fragment-ordered V tile
    __shared__ __align__(16) short pT[4][16 * 72];  // per-wave P C->A round trip

    // XCD swizzle: blockIdx.x = XCD slot (linear id % 8); each XCD owns 4 (b,h) pairs
    const int qtile  = blockIdx.y & 31;
    const int pairid = blockIdx.x * 4 + (blockIdx.y >> 5);
    const int h = pairid & 15;
    const int b = pairid >> 4;

    const int tid  = threadIdx.x;
    const int w    = tid >> 6;
    const int lane = tid & 63;
    const int quad = lane >> 4;
    const int r16  = lane & 15;
    const int qb   = qtile * QT;
    const int bh32 = (b * NH + h) * 32;

    // Q fragments (scale*log2e pre-folded by prepass)
    bf16x8 qfrag[2];
    {
        const short* qt_ = qw + (size_t)(bh32 + qtile) * 4096;
        qfrag[0] = *(const bf16x8*)(qt_ + (size_t)(w * 128 + lane) * 8);
        qfrag[1] = *(const bf16x8*)(qt_ + (size_t)(w * 128 + 64 + lane) * 8);
    }

    const float slope2 = __builtin_amdgcn_exp2f(-8.0f * (float)(h + 1) / (float)NH) * LOG2E;

    f32x4 O[4] = {{0,0,0,0},{0,0,0,0},{0,0,0,0},{0,0,0,0}};
    float m_run[4] = {-1e30f, -1e30f, -1e30f, -1e30f};
    float l_run[4] = {0.f, 0.f, 0.f, 0.f};

    const int kmin = (qb >= WINDOW - 1) ? (qb - (WINDOW - 1)) : 0;
    const int t0 = kmin >> 6;
    const int t1 = qtile;
    const int swz = quad ^ (r16 & 7);
    const int cb0 = w * 128;  // this wave's 128-chunk staging slice

    for (int kt = t0; kt <= t1; ++kt) {
        __syncthreads();    // prior tile's LDS reads done before DMA overwrites
        {
            const short* ktile = kw + (size_t)(bh32 + kt) * 4096;
            const short* vtile = vw + (size_t)(bh32 + kt) * 4096;
            async16(ktile + (size_t)(cb0 + lane) * 8,      &kS[cb0 * 8]);
            async16(ktile + (size_t)(cb0 + 64 + lane) * 8, &kS[(cb0 + 64) * 8]);
            async16(vtile + (size_t)(cb0 + lane) * 8,      &vS[cb0 * 8]);
            async16(vtile + (size_t)(cb0 + 64 + lane) * 8, &vS[(cb0 + 64) * 8]);
        }
        __syncthreads();    // drains vmcnt (DMA complete) + barrier

        // S = Q K^T (log2 units)
        f32x4 S[4];
        #pragma unroll
        for (int ct = 0; ct < 4; ++ct) {
            const int c0 = ((ct * 16 + r16) << 3) + swz;
            bf16x8 b0 = *(const bf16x8*)&kS[c0 * 8];        // e in [quad*8,+8)
            bf16x8 b1 = *(const bf16x8*)&kS[(c0 ^ 4) * 8];  // e in [32+quad*8,+8)
            f32x4 acc = {0.f, 0.f, 0.f, 0.f};
            acc = __builtin_amdgcn_mfma_f32_16x16x32_bf16(qfrag[0], b0, acc, 0, 0, 0);
            acc = __builtin_amdgcn_mfma_f32_16x16x32_bf16(qfrag[1], b1, acc, 0, 0, 0);
            S[ct] = acc;
        }

        // bias + mask; C-layout: q = quad*4 + r, k = ct*16 + r16
        const int q0 = qb + w * 16 + quad * 4;
        float p[4][4];
        float mt[4] = {-1e30f, -1e30f, -1e30f, -1e30f};
        #pragma unroll
        for (int ct = 0; ct < 4; ++ct) {
            const int kg = kt * KT + ct * 16 + r16;
            #pragma unroll
            for (int r = 0; r < 4; ++r) {
                const int dist = q0 + r - kg;
                float s2 = S[ct][r] - slope2 * (float)dist;
                if (dist < 0 || dist >= WINDOW) s2 = -1e30f;
                p[ct][r] = s2;
                mt[r] = fmaxf(mt[r], s2);
            }
        }
        #pragma unroll
        for (int d = 1; d < 16; d <<= 1) {
            #pragma unroll
            for (int r = 0; r < 4; ++r)
                mt[r] = fmaxf(mt[r], __shfl_xor(mt[r], d, 64));
        }

        float alpha[4], rs[4];
        #pragma unroll
        for (int r = 0; r < 4; ++r) {
            const float mn = fmaxf(m_run[r], mt[r]);
            alpha[r] = __builtin_amdgcn_exp2f(m_run[r] - mn);
            m_run[r] = mn;
            float s = 0.f;
            #pragma unroll
            for (int ct = 0; ct < 4; ++ct) {
                const float pe = __builtin_amdgcn_exp2f(p[ct][r] - mn);
                p[ct][r] = pe;
                s += pe;
            }
            rs[r] = s;
        }
        #pragma unroll
        for (int d = 1; d < 16; d <<= 1) {
            #pragma unroll
            for (int r = 0; r < 4; ++r)
                rs[r] += __shfl_xor(rs[r], d, 64);
        }
        #pragma unroll
        for (int r = 0; r < 4; ++r)
            l_run[r] = l_run[r] * alpha[r] + rs[r];
        #pragma unroll
        for (int et = 0; et < 4; ++et) {
            #pragma unroll
            for (int r = 0; r < 4; ++r)
                O[et][r] *= alpha[r];
        }

        // P: C-layout -> LDS -> A-layout (per-wave, same-wave DS in-order)
        short* pw = &pT[w][0];
        #pragma unroll
        for (int ct = 0; ct < 4; ++ct) {
            #pragma unroll
            for (int r = 0; r < 4; ++r)
                pw[(quad * 4 + r) * 72 + ct * 16 + r16] = f2bf(p[ct][r]);
        }
        bf16x8 aP0 = *(const bf16x8*)(pw + r16 * 72 + quad * 8);
        bf16x8 aP1 = *(const bf16x8*)(pw + r16 * 72 + 32 + quad * 8);

        // O += P V : frag (js*4+et) at vS chunk frag*64+lane (conflict-free)
        #pragma unroll
        for (int et = 0; et < 4; ++et) {
            bf16x8 v0 = *(const bf16x8*)&vS[(size_t)(et * 64 + lane) * 8];
            O[et] = __builtin_amdgcn_mfma_f32_16x16x32_bf16(aP0, v0, O[et], 0, 0, 0);
            bf16x8 v1 = *(const bf16x8*)&vS[(size_t)((4 + et) * 64 + lane) * 8];
            O[et] = __builtin_amdgcn_mfma_f32_16x16x32_bf16(aP1, v1, O[et], 0, 0, 0);
        }
    }

    float* obase = out + (((size_t)b * L_SEQ) * NH + (size_t)h) * EDIM;
    #pragma unroll
    for (int r = 0; r < 4; ++r) {
        const int qg = qb + w * 16 + quad * 4 + r;
        const float rl = 1.0f / l_run[r];
        float* orow = obase + (size_t)qg * (NH * EDIM);
        #pragma unroll
        for (int et = 0; et < 4; ++et)
            orow[et * 16 + r16] = O[et][r] * rl;
    }
}

// ---------------- fallback (round-1 kernel, used only if ws too small) ----------------
__global__ __launch_bounds__(256, 2) void flexattn_fwd_fb(
        const float* __restrict__ qkv, float* __restrict__ out) {
    __shared__ __align__(16) short kT[KT * 72];
    __shared__ __align__(16) short vB[8 * 64 * 8];
    __shared__ __align__(16) short pT[4][16 * 72];

    const int qtile = blockIdx.x;
    const int h     = blockIdx.y;
    const int b     = blockIdx.z;
    const int tid   = threadIdx.x;
    const int w     = tid >> 6;
    const int lane  = tid & 63;
    const int quad  = lane >> 4;
    const int r16   = lane & 15;
    const int qb = qtile * QT;
    const int rowstride = 3 * NH * EDIM;

    const float* qbase = qkv + ((size_t)b * L_SEQ * 3 + 0) * (NH * EDIM) + h * EDIM;
    const float* kbase = qkv + ((size_t)b * L_SEQ * 3 + 1) * (NH * EDIM) + h * EDIM;
    const float* vbase = qkv + ((size_t)b * L_SEQ * 3 + 2) * (NH * EDIM) + h * EDIM;

    const float qscale = 0.125f * LOG2E;
    bf16x8 qfrag[2];
    {
        const int qg = qb + w * 16 + r16;
        const float* qrow = qbase + (size_t)qg * rowstride;
        #pragma unroll
        for (int es = 0; es < 2; ++es) {
            const float* p = qrow + es * 32 + quad * 8;
            float4 a = *(const float4*)p;
            float4 c = *(const float4*)(p + 4);
            bf16x8 f;
            f[0] = f2bf(a.x * qscale); f[1] = f2bf(a.y * qscale);
            f[2] = f2bf(a.z * qscale); f[3] = f2bf(a.w * qscale);
            f[4] = f2bf(c.x * qscale); f[5] = f2bf(c.y * qscale);
            f[6] = f2bf(c.z * qscale); f[7] = f2bf(c.w * qscale);
            qfrag[es] = f;
        }
    }

    const float slope2 = __builtin_amdgcn_exp2f(-8.0f * (float)(h + 1) / (float)NH) * LOG2E;
    f32x4 O[4] = {{0,0,0,0},{0,0,0,0},{0,0,0,0},{0,0,0,0}};
    float m_run[4] = {-1e30f, -1e30f, -1e30f, -1e30f};
    float l_run[4] = {0.f, 0.f, 0.f, 0.f};

    const int kmin = (qb >= WINDOW - 1) ? (qb - (WINDOW - 1)) : 0;
    const int t0 = kmin >> 6;
    const int t1 = qtile;

    for (int kt = t0; kt <= t1; ++kt) {
        __syncthreads();
        {
            const int j = tid >> 2;
            const int ebase = (tid & 3) * 16;
            const float* krow = kbase + (size_t)(kt * KT + j) * rowstride + ebase;
            const float* vrow = vbase + (size_t)(kt * KT + j) * rowstride + ebase;
            const int js = j >> 5, qd = (j >> 3) & 3, ii = j & 7;
            #pragma unroll
            for (int ee = 0; ee < 4; ++ee) {
                const int e = ebase + ee * 4;
                float4 k4 = *(const float4*)(krow + ee * 4);
                short* kd = &kT[j * 72 + e];
                kd[0] = f2bf(k4.x); kd[1] = f2bf(k4.y);
                kd[2] = f2bf(k4.z); kd[3] = f2bf(k4.w);
                float4 v4 = *(const float4*)(vrow + ee * 4);
                const int et = e >> 4;
                const int ln = qd * 16 + (e & 15);
                short* vd = &vB[(((js * 4 + et) * 64) + ln) * 8 + ii];
                vd[0]  = f2bf(v4.x);
                vd[8]  = f2bf(v4.y);
                vd[16] = f2bf(v4.z);
                vd[24] = f2bf(v4.w);
            }
        }
        __syncthreads();

        f32x4 S[4];
        #pragma unroll
        for (int ct = 0; ct < 4; ++ct) {
            const short* kr = &kT[(ct * 16 + r16) * 72 + quad * 8];
            bf16x8 b0 = *(const bf16x8*)kr;
            bf16x8 b1 = *(const bf16x8*)(kr + 32);
            f32x4 acc = {0.f, 0.f, 0.f, 0.f};
            acc = __builtin_amdgcn_mfma_f32_16x16x32_bf16(qfrag[0], b0, acc, 0, 0, 0);
            acc = __builtin_amdgcn_mfma_f32_16x16x32_bf16(qfrag[1], b1, acc, 0, 0, 0);
            S[ct] = acc;
        }

        const int q0 = qb + w * 16 + quad * 4;
        float p[4][4];
        float mt[4] = {-1e30f, -1e30f, -1e30f, -1e30f};
        #pragma unroll
        for (int ct = 0; ct < 4; ++ct) {
            const int kg = kt * KT + ct * 16 + r16;
            #pragma unroll
            for (int r = 0; r < 4; ++r) {
                const int dist = q0 + r - kg;
                float s2 = S[ct][r] - slope2 * (float)dist;
                if (dist < 0 || dist >= WINDOW) s2 = -1e30f;
                p[ct][r] = s2;
                mt[r] = fmaxf(mt[r], s2);
            }
        }
        #pragma unroll
        for (int d = 1; d < 16; d <<= 1) {
            #pragma unroll
            for (int r = 0; r < 4; ++r)
                mt[r] = fmaxf(mt[r], __shfl_xor(mt[r], d, 64));
        }

        float alpha[4], rs[4];
        #pragma unroll
        for (int r = 0; r < 4; ++r) {
            const float mn = fmaxf(m_run[r], mt[r]);
            alpha[r] = __builtin_amdgcn_exp2f(m_run[r] - mn);
            m_run[r] = mn;
            float s = 0.f;
            #pragma unroll
            for (int ct = 0; ct < 4; ++ct) {
                const float pe = __builtin_amdgcn_exp2f(p[ct][r] - mn);
                p[ct][r] = pe;
                s += pe;
            }
            rs[r] = s;
        }
        #pragma unroll
        for (int d = 1; d < 16; d <<= 1) {
            #pragma unroll
            for (int r = 0; r < 4; ++r)
                rs[r] += __shfl_xor(rs[r], d, 64);
        }
        #pragma unroll
        for (int r = 0; r < 4; ++r)
            l_run[r] = l_run[r] * alpha[r] + rs[r];
        #pragma unroll
        for (int et = 0; et < 4; ++et) {
            #pragma unroll
            for (int r = 0; r < 4; ++r)
                O[et][r] *= alpha[r];
        }

        short* pw = &pT[w][0];
        #pragma unroll
        for (int ct = 0; ct < 4; ++ct) {
            #pragma unroll
            for (int r = 0; r < 4; ++r)
                pw[(quad * 4 + r) * 72 + ct * 16 + r16] = f2bf(p[ct][r]);
        }
        bf16x8 aP0 = *(const bf16x8*)(pw + r16 * 72 + quad * 8);
        bf16x8 aP1 = *(const bf16x8*)(pw + r16 * 72 + 32 + quad * 8);

        #pragma unroll
        for (int et = 0; et < 4; ++et) {
            bf16x8 v0 = *(const bf16x8*)(&vB[((0 * 4 + et) * 64 + lane) * 8]);
            O[et] = __builtin_amdgcn_mfma_f32_16x16x32_bf16(aP0, v0, O[et], 0, 0, 0);
            bf16x8 v1 = *(const bf16x8*)(&vB[((1 * 4 + et) * 64 + lane) * 8]);
            O[et] = __builtin_amdgcn_mfma_f32_16x16x32_bf16(aP1, v1, O[et], 0, 0, 0);
        }
    }

    float* obase = out + (((size_t)b * L_SEQ) * NH + (size_t)h) * EDIM;
    #pragma unroll
    for (int r = 0; r < 4; ++r) {
        const int qg = qb + w * 16 + quad * 4 + r;
        const float rl = 1.0f / l_run[r];
        float* orow = obase + (size_t)qg * (NH * EDIM);
        #pragma unroll
        for (int et = 0; et < 4; ++et)
            orow[et * 16 + r16] = O[et][r] * rl;
    }
}

extern "C" void kernel_launch(void* const* d_in, const int* in_sizes, int n_in,
                              void* d_out, int out_size, void* d_ws, size_t ws_size,
                              hipStream_t stream) {
    const float* qkv = (const float*)d_in[0];
    float* out = (float*)d_out;
    const size_t need = (size_t)3 * 1024 * 4096 * sizeof(short);  // 25.2 MB
    if (ws_size >= need) {
        short* qw = (short*)d_ws;
        short* kw = qw + (size_t)1024 * 4096;
        short* vw = kw + (size_t)1024 * 4096;
        prepass<<<1024, 256, 0, stream>>>(qkv, qw, kw, vw);
        dim3 grid(8, 128);
        flexattn_fwd2<<<grid, 256, 0, stream>>>(qw, kw, vw, out);
    } else {
        dim3 grid(L_SEQ / QT, NH, 2);
        flexattn_fwd_fb<<<grid, 256, 0, stream>>>(qkv, out);
    }
}

// Round 3
// 122.913 us; speedup vs baseline: 1.3208x; 1.2349x over previous
//
#include <hip/hip_runtime.h>
#include <cstdint>

#define L_SEQ 2048
#define NH 16
#define EDIM 64
#define WINDOW 1024
#define QT 64
#define KT 64
#define LOG2E 1.4426950408889634f
#define M_FIX 16.0f   // fixed softmax max in log2 domain (scores bounded ~|10|)

typedef short bf16x8 __attribute__((ext_vector_type(8)));
typedef float f32x4 __attribute__((ext_vector_type(4)));

__device__ __forceinline__ short f2bf(float x) {   // RNE
    uint32_t u = __builtin_bit_cast(uint32_t, x);
    uint32_t r = (u + 0x7fffu + ((u >> 16) & 1u)) >> 16;
    return (short)(r & 0xffffu);
}
__device__ __forceinline__ short f2bf_trunc(float x) {
    return (short)(__builtin_bit_cast(uint32_t, x) >> 16);
}

// async 16B/lane global->LDS: LDS dest = wave-uniform base + lane*16 (m104/m108)
__device__ __forceinline__ void async16(const short* g, const short* l) {
    __builtin_amdgcn_global_load_lds(
        (const __attribute__((address_space(1))) void*)(uintptr_t)(g),
        (__attribute__((address_space(3))) void*)(uintptr_t)(l),
        16, 0, 0);
}

// ---------------- pre-pass v2: one block per (b,h,tile) ----------------
// Chunk layouts (16B chunks, 512 per tensor-tile) consumed by the attention kernel:
//  Q chunk c : Q[(c>>7)*16 + (c&15)][((c>>6)&1)*32 + ((c>>4)&3)*8 + j] * qscale
//  K chunk c : row=c>>3, cc=(c&7)^(row&7) : K[row][cc*8 + j]   (XOR swizzle)
//  V chunk c : frag=c>>6, l6=c&63 : V[(frag>>2)*32 + (l6>>4)*8 + j][(frag&3)*16 + (l6&15)]
__global__ __launch_bounds__(256) void prepass2(const float* __restrict__ qkv,
        short* __restrict__ qw, short* __restrict__ kw, short* __restrict__ vw) {
    __shared__ float vt[64][65];   // vt[e][row], pad 65 -> 2-way-free writes, b128 reads
    const int x = blockIdx.x;      // 1024 blocks
    const int b = x >> 9, tile = (x >> 4) & 31, h = x & 15;
    const int tid = threadIdx.x;
    const int tg = (b * NH + h) * 32 + tile;
    const float* base = qkv + (size_t)b * (L_SEQ * 3072) + (size_t)tile * 64 * 3072 + h * 64;
    const float qscale = 0.125f * LOG2E;
    short* qo = qw + (size_t)tg * 4096;
    short* ko = kw + (size_t)tg * 4096;
    short* vo = vw + (size_t)tg * 4096;

    // Q: per row, 8 chunks cover one contiguous 256B span -> full-line reads
    #pragma unroll
    for (int it = 0; it < 2; ++it) {
        const int c = tid + it * 256;
        const int row = ((c >> 7) << 4) + (c & 15);
        const int e0  = (((c >> 6) & 1) << 5) + (((c >> 4) & 3) << 3);
        const float* src = base + (size_t)row * 3072 + e0;
        float4 a = *(const float4*)src, d = *(const float4*)(src + 4);
        short* o = qo + (size_t)c * 8;
        o[0] = f2bf(a.x * qscale); o[1] = f2bf(a.y * qscale);
        o[2] = f2bf(a.z * qscale); o[3] = f2bf(a.w * qscale);
        o[4] = f2bf(d.x * qscale); o[5] = f2bf(d.y * qscale);
        o[6] = f2bf(d.z * qscale); o[7] = f2bf(d.w * qscale);
    }
    // K (XOR-swizzled chunk order)
    #pragma unroll
    for (int it = 0; it < 2; ++it) {
        const int c = tid + it * 256;
        const int row = c >> 3, cc = (c & 7) ^ (row & 7);
        const float* src = base + (size_t)row * 3072 + 1024 + cc * 8;
        float4 a = *(const float4*)src, d = *(const float4*)(src + 4);
        short* o = ko + (size_t)c * 8;
        o[0] = f2bf(a.x); o[1] = f2bf(a.y); o[2] = f2bf(a.z); o[3] = f2bf(a.w);
        o[4] = f2bf(d.x); o[5] = f2bf(d.y); o[6] = f2bf(d.z); o[7] = f2bf(d.w);
    }
    // V: coalesced row reads -> transposed LDS -> B-fragment chunks
    {
        const int row = tid >> 2, e0 = (tid & 3) << 4;
        const float* src = base + (size_t)row * 3072 + 2048 + e0;
        #pragma unroll
        for (int q4 = 0; q4 < 4; ++q4) {
            float4 a = *(const float4*)(src + q4 * 4);
            vt[e0 + q4 * 4 + 0][row] = a.x;
            vt[e0 + q4 * 4 + 1][row] = a.y;
            vt[e0 + q4 * 4 + 2][row] = a.z;
            vt[e0 + q4 * 4 + 3][row] = a.w;
        }
    }
    __syncthreads();
    #pragma unroll
    for (int it = 0; it < 2; ++it) {
        const int c = tid + it * 256;
        const int frag = c >> 6, l6 = c & 63;
        const int col = (frag & 3) * 16 + (l6 & 15);
        const int row0 = (frag >> 2) * 32 + ((l6 >> 4) & 3) * 8;
        const float* p = &vt[col][row0];   // 8 consecutive floats = 2x ds_read_b128
        bf16x8 o8;
        #pragma unroll
        for (int j = 0; j < 8; ++j) o8[j] = f2bf(p[j]);
        *(bf16x8*)(vo + (size_t)c * 8) = o8;
    }
}

// ---------------- attention v3: fixed-max softmax, dbuf DMA, mask-specialized ----------------
__global__ __launch_bounds__(256, 2) void flexattn_fwd3(
        const short* __restrict__ qw, const short* __restrict__ kw,
        const short* __restrict__ vw, float* __restrict__ out) {
    __shared__ __align__(16) short kS[2][64 * 64];
    __shared__ __align__(16) short vS[2][512 * 8];
    __shared__ __align__(16) short pT[4][16 * 72];

    // XCD swizzle: blockIdx.x = linear%8 = XCD slot; qtile descending (LPT)
    const int qtile  = 31 - (blockIdx.y & 31);
    const int pairid = blockIdx.x * 4 + (blockIdx.y >> 5);
    const int h = pairid & 15;
    const int b = pairid >> 4;

    const int tid  = threadIdx.x;
    const int w    = tid >> 6;
    const int lane = tid & 63;
    const int quad = lane >> 4;
    const int r16  = lane & 15;
    const int qb   = qtile * QT;
    const int bh32 = (b * NH + h) * 32;

    bf16x8 qfrag[2];
    {
        const short* qt_ = qw + (size_t)(bh32 + qtile) * 4096;
        qfrag[0] = *(const bf16x8*)(qt_ + (size_t)(w * 128 + lane) * 8);
        qfrag[1] = *(const bf16x8*)(qt_ + (size_t)(w * 128 + 64 + lane) * 8);
    }

    const float slope2 = __builtin_amdgcn_exp2f(-8.0f * (float)(h + 1) / (float)NH) * LOG2E;
    // c16[ct*4+r] = M_FIX + slope2*(r - ct*16): per-element bias constant across tiles
    float c16[16];
    #pragma unroll
    for (int ct = 0; ct < 4; ++ct)
        #pragma unroll
        for (int r = 0; r < 4; ++r)
            c16[ct * 4 + r] = M_FIX + slope2 * (float)(r - ct * 16);

    f32x4 O[4] = {{0,0,0,0},{0,0,0,0},{0,0,0,0},{0,0,0,0}};
    float rs4[4] = {0.f, 0.f, 0.f, 0.f};

    const int t0q = (qb >= WINDOW - 1) ? ((qb - (WINDOW - 1)) >> 6) : 0;
    const int t1  = qtile;
    const int swz = quad ^ (r16 & 7);
    const int cb0 = w * 128;
    const int q0  = qb + w * 16 + quad * 4;

    // prefetch first tile into buf 0
    {
        const short* ktile = kw + (size_t)(bh32 + t0q) * 4096;
        const short* vtile = vw + (size_t)(bh32 + t0q) * 4096;
        async16(ktile + (size_t)(cb0 + lane) * 8,      &kS[0][cb0 * 8]);
        async16(ktile + (size_t)(cb0 + 64 + lane) * 8, &kS[0][(cb0 + 64) * 8]);
        async16(vtile + (size_t)(cb0 + lane) * 8,      &vS[0][cb0 * 8]);
        async16(vtile + (size_t)(cb0 + 64 + lane) * 8, &vS[0][(cb0 + 64) * 8]);
    }

    for (int kt = t0q; kt <= t1; ++kt) {
        const int cur = (kt - t0q) & 1;
        __syncthreads();   // drains DMA(kt) (vmcnt 0) + protects buf cur^1 for prefetch
        if (kt < t1) {     // prefetch kt+1 into the other buffer; drained at NEXT barrier
            const int nb = cur ^ 1;
            const short* ktile = kw + (size_t)(bh32 + kt + 1) * 4096;
            const short* vtile = vw + (size_t)(bh32 + kt + 1) * 4096;
            async16(ktile + (size_t)(cb0 + lane) * 8,      &kS[nb][cb0 * 8]);
            async16(ktile + (size_t)(cb0 + 64 + lane) * 8, &kS[nb][(cb0 + 64) * 8]);
            async16(vtile + (size_t)(cb0 + lane) * 8,      &vS[nb][cb0 * 8]);
            async16(vtile + (size_t)(cb0 + 64 + lane) * 8, &vS[nb][(cb0 + 64) * 8]);
        }

        // S = Q K^T (log2 units; scale*log2e folded into Q)
        f32x4 S[4];
        #pragma unroll
        for (int ct = 0; ct < 4; ++ct) {
            const int c0 = ((ct * 16 + r16) << 3) + swz;
            bf16x8 b0 = *(const bf16x8*)&kS[cur][c0 * 8];
            bf16x8 b1 = *(const bf16x8*)&kS[cur][(c0 ^ 4) * 8];
            f32x4 acc = {0.f, 0.f, 0.f, 0.f};
            acc = __builtin_amdgcn_mfma_f32_16x16x32_bf16(qfrag[0], b0, acc, 0, 0, 0);
            acc = __builtin_amdgcn_mfma_f32_16x16x32_bf16(qfrag[1], b1, acc, 0, 0, 0);
            S[ct] = acc;
        }

        // p = exp2(S - slope2*dist - M_FIX); no running max, no rescale
        const float bb = slope2 * (float)(q0 - r16 - kt * 64);
        float p[4][4];
        if (kt != t0q && kt != t1) {         // middle tiles: no mask possible
            #pragma unroll
            for (int ct = 0; ct < 4; ++ct)
                #pragma unroll
                for (int r = 0; r < 4; ++r) {
                    const float pe = __builtin_amdgcn_exp2f(S[ct][r] - bb - c16[ct * 4 + r]);
                    p[ct][r] = pe;
                    rs4[r] += pe;
                }
        } else {                              // first tile (dist>=W) / diagonal (dist<0)
            const int kg0 = kt * 64 + r16;
            #pragma unroll
            for (int ct = 0; ct < 4; ++ct)
                #pragma unroll
                for (int r = 0; r < 4; ++r) {
                    const int dist = q0 + r - (kg0 + ct * 16);
                    float pe = __builtin_amdgcn_exp2f(S[ct][r] - bb - c16[ct * 4 + r]);
                    pe = (dist < 0 || dist >= WINDOW) ? 0.0f : pe;
                    p[ct][r] = pe;
                    rs4[r] += pe;
                }
        }

        // P: C-layout -> LDS -> A-layout (per-wave buffer, same-wave DS in-order)
        short* pw = &pT[w][0];
        #pragma unroll
        for (int ct = 0; ct < 4; ++ct)
            #pragma unroll
            for (int r = 0; r < 4; ++r)
                pw[(quad * 4 + r) * 72 + ct * 16 + r16] = f2bf_trunc(p[ct][r]);
        bf16x8 aP0 = *(const bf16x8*)(pw + r16 * 72 + quad * 8);
        bf16x8 aP1 = *(const bf16x8*)(pw + r16 * 72 + 32 + quad * 8);

        // O += P V
        #pragma unroll
        for (int et = 0; et < 4; ++et) {
            bf16x8 v0 = *(const bf16x8*)&vS[cur][(size_t)(et * 64 + lane) * 8];
            O[et] = __builtin_amdgcn_mfma_f32_16x16x32_bf16(aP0, v0, O[et], 0, 0, 0);
            bf16x8 v1 = *(const bf16x8*)&vS[cur][(size_t)((4 + et) * 64 + lane) * 8];
            O[et] = __builtin_amdgcn_mfma_f32_16x16x32_bf16(aP1, v1, O[et], 0, 0, 0);
        }
    }

    // one final row-sum reduction across the 16-lane k-groups
    #pragma unroll
    for (int d = 1; d < 16; d <<= 1)
        #pragma unroll
        for (int r = 0; r < 4; ++r)
            rs4[r] += __shfl_xor(rs4[r], d, 64);

    float* obase = out + (((size_t)b * L_SEQ) * NH + (size_t)h) * EDIM;
    #pragma unroll
    for (int r = 0; r < 4; ++r) {
        const int qg = qb + w * 16 + quad * 4 + r;
        const float rl = 1.0f / rs4[r];
        float* orow = obase + (size_t)qg * (NH * EDIM);
        #pragma unroll
        for (int et = 0; et < 4; ++et)
            orow[et * 16 + r16] = O[et][r] * rl;
    }
}

// ---------------- fallback (round-1 kernel, used only if ws too small) ----------------
__global__ __launch_bounds__(256, 2) void flexattn_fwd_fb(
        const float* __restrict__ qkv, float* __restrict__ out) {
    __shared__ __align__(16) short kT[KT * 72];
    __shared__ __align__(16) short vB[8 * 64 * 8];
    __shared__ __align__(16) short pT[4][16 * 72];

    const int qtile = blockIdx.x;
    const int h     = blockIdx.y;
    const int b     = blockIdx.z;
    const int tid   = threadIdx.x;
    const int w     = tid >> 6;
    const int lane  = tid & 63;
    const int quad  = lane >> 4;
    const int r16   = lane & 15;
    const int qb = qtile * QT;
    const int rowstride = 3 * NH * EDIM;

    const float* qbase = qkv + ((size_t)b * L_SEQ * 3 + 0) * (NH * EDIM) + h * EDIM;
    const float* kbase = qkv + ((size_t)b * L_SEQ * 3 + 1) * (NH * EDIM) + h * EDIM;
    const float* vbase = qkv + ((size_t)b * L_SEQ * 3 + 2) * (NH * EDIM) + h * EDIM;

    const float qscale = 0.125f * LOG2E;
    bf16x8 qfrag[2];
    {
        const int qg = qb + w * 16 + r16;
        const float* qrow = qbase + (size_t)qg * rowstride;
        #pragma unroll
        for (int es = 0; es < 2; ++es) {
            const float* p = qrow + es * 32 + quad * 8;
            float4 a = *(const float4*)p;
            float4 c = *(const float4*)(p + 4);
            bf16x8 f;
            f[0] = f2bf(a.x * qscale); f[1] = f2bf(a.y * qscale);
            f[2] = f2bf(a.z * qscale); f[3] = f2bf(a.w * qscale);
            f[4] = f2bf(c.x * qscale); f[5] = f2bf(c.y * qscale);
            f[6] = f2bf(c.z * qscale); f[7] = f2bf(c.w * qscale);
            qfrag[es] = f;
        }
    }

    const float slope2 = __builtin_amdgcn_exp2f(-8.0f * (float)(h + 1) / (float)NH) * LOG2E;
    f32x4 O[4] = {{0,0,0,0},{0,0,0,0},{0,0,0,0},{0,0,0,0}};
    float m_run[4] = {-1e30f, -1e30f, -1e30f, -1e30f};
    float l_run[4] = {0.f, 0.f, 0.f, 0.f};

    const int kmin = (qb >= WINDOW - 1) ? (qb - (WINDOW - 1)) : 0;
    const int t0 = kmin >> 6;
    const int t1 = qtile;

    for (int kt = t0; kt <= t1; ++kt) {
        __syncthreads();
        {
            const int j = tid >> 2;
            const int ebase = (tid & 3) * 16;
            const float* krow = kbase + (size_t)(kt * KT + j) * rowstride + ebase;
            const float* vrow = vbase + (size_t)(kt * KT + j) * rowstride + ebase;
            const int js = j >> 5, qd = (j >> 3) & 3, ii = j & 7;
            #pragma unroll
            for (int ee = 0; ee < 4; ++ee) {
                const int e = ebase + ee * 4;
                float4 k4 = *(const float4*)(krow + ee * 4);
                short* kd = &kT[j * 72 + e];
                kd[0] = f2bf(k4.x); kd[1] = f2bf(k4.y);
                kd[2] = f2bf(k4.z); kd[3] = f2bf(k4.w);
                float4 v4 = *(const float4*)(vrow + ee * 4);
                const int et = e >> 4;
                const int ln = qd * 16 + (e & 15);
                short* vd = &vB[(((js * 4 + et) * 64) + ln) * 8 + ii];
                vd[0]  = f2bf(v4.x);
                vd[8]  = f2bf(v4.y);
                vd[16] = f2bf(v4.z);
                vd[24] = f2bf(v4.w);
            }
        }
        __syncthreads();

        f32x4 S[4];
        #pragma unroll
        for (int ct = 0; ct < 4; ++ct) {
            const short* kr = &kT[(ct * 16 + r16) * 72 + quad * 8];
            bf16x8 b0 = *(const bf16x8*)kr;
            bf16x8 b1 = *(const bf16x8*)(kr + 32);
            f32x4 acc = {0.f, 0.f, 0.f, 0.f};
            acc = __builtin_amdgcn_mfma_f32_16x16x32_bf16(qfrag[0], b0, acc, 0, 0, 0);
            acc = __builtin_amdgcn_mfma_f32_16x16x32_bf16(qfrag[1], b1, acc, 0, 0, 0);
            S[ct] = acc;
        }

        const int q0 = qb + w * 16 + quad * 4;
        float p[4][4];
        float mt[4] = {-1e30f, -1e30f, -1e30f, -1e30f};
        #pragma unroll
        for (int ct = 0; ct < 4; ++ct) {
            const int kg = kt * KT + ct * 16 + r16;
            #pragma unroll
            for (int r = 0; r < 4; ++r) {
                const int dist = q0 + r - kg;
                float s2 = S[ct][r] - slope2 * (float)dist;
                if (dist < 0 || dist >= WINDOW) s2 = -1e30f;
                p[ct][r] = s2;
                mt[r] = fmaxf(mt[r], s2);
            }
        }
        #pragma unroll
        for (int d = 1; d < 16; d <<= 1) {
            #pragma unroll
            for (int r = 0; r < 4; ++r)
                mt[r] = fmaxf(mt[r], __shfl_xor(mt[r], d, 64));
        }

        float alpha[4], rs[4];
        #pragma unroll
        for (int r = 0; r < 4; ++r) {
            const float mn = fmaxf(m_run[r], mt[r]);
            alpha[r] = __builtin_amdgcn_exp2f(m_run[r] - mn);
            m_run[r] = mn;
            float s = 0.f;
            #pragma unroll
            for (int ct = 0; ct < 4; ++ct) {
                const float pe = __builtin_amdgcn_exp2f(p[ct][r] - mn);
                p[ct][r] = pe;
                s += pe;
            }
            rs[r] = s;
        }
        #pragma unroll
        for (int d = 1; d < 16; d <<= 1) {
            #pragma unroll
            for (int r = 0; r < 4; ++r)
                rs[r] += __shfl_xor(rs[r], d, 64);
        }
        #pragma unroll
        for (int r = 0; r < 4; ++r)
            l_run[r] = l_run[r] * alpha[r] + rs[r];
        #pragma unroll
        for (int et = 0; et < 4; ++et) {
            #pragma unroll
            for (int r = 0; r < 4; ++r)
                O[et][r] *= alpha[r];
        }

        short* pw = &pT[w][0];
        #pragma unroll
        for (int ct = 0; ct < 4; ++ct) {
            #pragma unroll
            for (int r = 0; r < 4; ++r)
                pw[(quad * 4 + r) * 72 + ct * 16 + r16] = f2bf(p[ct][r]);
        }
        bf16x8 aP0 = *(const bf16x8*)(pw + r16 * 72 + quad * 8);
        bf16x8 aP1 = *(const bf16x8*)(pw + r16 * 72 + 32 + quad * 8);

        #pragma unroll
        for (int et = 0; et < 4; ++et) {
            bf16x8 v0 = *(const bf16x8*)(&vB[((0 * 4 + et) * 64 + lane) * 8]);
            O[et] = __builtin_amdgcn_mfma_f32_16x16x32_bf16(aP0, v0, O[et], 0, 0, 0);
            bf16x8 v1 = *(const bf16x8*)(&vB[((1 * 4 + et) * 64 + lane) * 8]);
            O[et] = __builtin_amdgcn_mfma_f32_16x16x32_bf16(aP1, v1, O[et], 0, 0, 0);
        }
    }

    float* obase = out + (((size_t)b * L_SEQ) * NH + (size_t)h) * EDIM;
    #pragma unroll
    for (int r = 0; r < 4; ++r) {
        const int qg = qb + w * 16 + quad * 4 + r;
        const float rl = 1.0f / l_run[r];
        float* orow = obase + (size_t)qg * (NH * EDIM);
        #pragma unroll
        for (int et = 0; et < 4; ++et)
            orow[et * 16 + r16] = O[et][r] * rl;
    }
}

extern "C" void kernel_launch(void* const* d_in, const int* in_sizes, int n_in,
                              void* d_out, int out_size, void* d_ws, size_t ws_size,
                              hipStream_t stream) {
    const float* qkv = (const float*)d_in[0];
    float* out = (float*)d_out;
    const size_t need = (size_t)3 * 1024 * 4096 * sizeof(short);  // 25.2 MB
    if (ws_size >= need) {
        short* qw = (short*)d_ws;
        short* kw = qw + (size_t)1024 * 4096;
        short* vw = kw + (size_t)1024 * 4096;
        prepass2<<<1024, 256, 0, stream>>>(qkv, qw, kw, vw);
        dim3 grid(8, 128);
        flexattn_fwd3<<<grid, 256, 0, stream>>>(qw, kw, vw, out);
    } else {
        dim3 grid(L_SEQ / QT, NH, 2);
        flexattn_fwd_fb<<<grid, 256, 0, stream>>>(qkv, out);
    }
}